// Round 1
// baseline (705.758 us; speedup 1.0000x reference)
//
#include <hip/hip_runtime.h>
#include <hip/hip_bf16.h>
#include <stdint.h>

#define BB 8192
#define DIM 256

typedef unsigned short u16;
typedef __attribute__((ext_vector_type(8))) short bf16x8;   // 8 bf16 = 4 VGPRs
typedef __attribute__((ext_vector_type(4))) float f32x4;

// monotone float -> uint mapping (order-preserving), so atomicMax(uint) == float max
__device__ __forceinline__ unsigned fmap(float f) {
  unsigned u = __float_as_uint(f);
  return (u & 0x80000000u) ? ~u : (u | 0x80000000u);
}

__device__ __forceinline__ u16 f2bf(float f) {
  __hip_bfloat16 h = __float2bfloat16(f);   // RTNE
  union { __hip_bfloat16 h; u16 u; } cvt;
  cvt.h = h;
  return cvt.u;
}

// ---------------------------------------------------------------------------
// Phase 1: one wave per row. Computes all row-wise dots/norms, loss partial
// sums, fp32 diagonal sims, and writes 4 normalized bf16 matrices to ws.
// ---------------------------------------------------------------------------
__global__ __launch_bounds__(256) void phase1(
    const float* __restrict__ vp,  const float* __restrict__ tp,
    const float* __restrict__ vfp, const float* __restrict__ ce,
    const float* __restrict__ nr,
    float* __restrict__ lossSums, float* __restrict__ diag,
    u16* __restrict__ vbuf, u16* __restrict__ gvbuf,
    u16* __restrict__ nvbuf, u16* __restrict__ gtbuf) {
  const int wave = threadIdx.x >> 6;
  const int lane = threadIdx.x & 63;
  const int row  = blockIdx.x * 4 + wave;
  const int base = row * DIM + lane * 4;

  float4 a = *(const float4*)&vp[base];
  float4 t = *(const float4*)&tp[base];
  float4 g = *(const float4*)&vfp[base];
  float4 c = *(const float4*)&ce[base];
  float4 n = *(const float4*)&nr[base];

  float s[10];
  s[0] = a.x*a.x + a.y*a.y + a.z*a.z + a.w*a.w;  // |vp|^2
  s[1] = g.x*g.x + g.y*g.y + g.z*g.z + g.w*g.w;  // |vfp|^2
  s[2] = a.x*g.x + a.y*g.y + a.z*g.z + a.w*g.w;  // vp.vfp
  s[3] = t.x*t.x + t.y*t.y + t.z*t.z + t.w*t.w;  // |tp|^2
  s[4] = c.x*c.x + c.y*c.y + c.z*c.z + c.w*c.w;  // |ce|^2
  s[5] = t.x*c.x + t.y*c.y + t.z*c.z + t.w*c.w;  // tp.ce
  s[6] = n.x*n.x + n.y*n.y + n.z*n.z + n.w*n.w;  // |narr|^2
  s[7] = g.x*c.x + g.y*c.y + g.z*c.z + g.w*c.w;  // vfp.ce
  s[8] = a.x*c.x + a.y*c.y + a.z*c.z + a.w*c.w;  // vp.ce
  s[9] = n.x*c.x + n.y*c.y + n.z*c.z + n.w*c.w;  // narr.ce

  #pragma unroll
  for (int mk = 1; mk < 64; mk <<= 1) {
    #pragma unroll
    for (int q = 0; q < 10; ++q) s[q] += __shfl_xor(s[q], mk);
  }

  const float eps = 1e-8f;
  float na = fmaxf(sqrtf(s[0]), eps);
  float ng = fmaxf(sqrtf(s[1]), eps);
  float nt = fmaxf(sqrtf(s[3]), eps);
  float nc = fmaxf(sqrtf(s[4]), eps);
  float nn = fmaxf(sqrtf(s[6]), eps);

  float ia = 1.f / na, ig = 1.f / ng, ic = 1.f / nc, in_ = 1.f / nn;

  ushort4* v4  = (ushort4*)vbuf;
  ushort4* gv4 = (ushort4*)gvbuf;
  ushort4* nv4 = (ushort4*)nvbuf;
  ushort4* gt4 = (ushort4*)gtbuf;
  int idx = row * 64 + lane;
  v4[idx]  = make_ushort4(f2bf(a.x*ia),  f2bf(a.y*ia),  f2bf(a.z*ia),  f2bf(a.w*ia));
  gv4[idx] = make_ushort4(f2bf(g.x*ig),  f2bf(g.y*ig),  f2bf(g.z*ig),  f2bf(g.w*ig));
  nv4[idx] = make_ushort4(f2bf(n.x*in_), f2bf(n.y*in_), f2bf(n.z*in_), f2bf(n.w*in_));
  gt4[idx] = make_ushort4(f2bf(c.x*ic),  f2bf(c.y*ic),  f2bf(c.z*ic),  f2bf(c.w*ic));

  if (lane == 0) {
    atomicAdd(&lossSums[0], s[2] / (na * ng));
    atomicAdd(&lossSums[1], s[5] / (nt * nc));
    diag[0 * BB + row] = s[7] / (ng * nc);   // gt_v . gt_t
    diag[1 * BB + row] = s[8] / (na * nc);   // v    . gt_t
    diag[2 * BB + row] = s[9] / (nn * nc);   // narr . gt_t
  }
}

// ---------------------------------------------------------------------------
// Phase 2: fused bf16-MFMA B^T GEMM + per-row LT/GT running max.
// 128x128 block tile, 4 waves (2x2 of 64x64), 16x16x32 MFMA, K=256 in 4
// stages of BK=64. grid.z selects which A matrix (gt_v / v / narr_v).
// ---------------------------------------------------------------------------
#define PADK 72   // 64 + 8: row stride in LDS elements, kills bank conflicts

__global__ __launch_bounds__(256) void sim_argmax(
    const u16* __restrict__ A0, const u16* __restrict__ A1,
    const u16* __restrict__ A2, const u16* __restrict__ B,
    unsigned* __restrict__ maxLT, unsigned* __restrict__ maxGT) {
  __shared__ u16 As[128][PADK];
  __shared__ u16 Bs[128][PADK];

  const int tid  = threadIdx.x;
  const int lane = tid & 63;
  const int wave = tid >> 6;
  const int wr   = wave >> 1, wc = wave & 1;
  const int m    = lane & 15, quad = lane >> 4;
  const int z    = blockIdx.z;

  const u16* A = (z == 0) ? A0 : (z == 1) ? A1 : A2;
  const int rowTile = blockIdx.y * 128;
  const int colTile = blockIdx.x * 128;

  f32x4 acc[4][4];
  #pragma unroll
  for (int i = 0; i < 4; ++i)
    #pragma unroll
    for (int j = 0; j < 4; ++j) acc[i][j] = (f32x4){0.f, 0.f, 0.f, 0.f};

  for (int s = 0; s < 4; ++s) {
    const int k0 = s * 64;
    if (s) __syncthreads();
    // stage 128 rows x 64 cols of both A and B: 1024 16B chunks each
    #pragma unroll
    for (int it = 0; it < 4; ++it) {
      int tch = tid + it * 256;
      int row = tch >> 3, kc = tch & 7;
      *(uint4*)&As[row][kc * 8] =
          *(const uint4*)&A[(size_t)(rowTile + row) * DIM + k0 + kc * 8];
      *(uint4*)&Bs[row][kc * 8] =
          *(const uint4*)&B[(size_t)(colTile + row) * DIM + k0 + kc * 8];
    }
    __syncthreads();

    #pragma unroll
    for (int kk = 0; kk < 2; ++kk) {
      bf16x8 af[4], bf[4];
      #pragma unroll
      for (int rt = 0; rt < 4; ++rt)
        af[rt] = *(const bf16x8*)&As[wr * 64 + rt * 16 + m][kk * 32 + quad * 8];
      #pragma unroll
      for (int ct = 0; ct < 4; ++ct)
        bf[ct] = *(const bf16x8*)&Bs[wc * 64 + ct * 16 + m][kk * 32 + quad * 8];
      #pragma unroll
      for (int rt = 0; rt < 4; ++rt)
        #pragma unroll
        for (int ct = 0; ct < 4; ++ct)
          acc[rt][ct] = __builtin_amdgcn_mfma_f32_16x16x32_bf16(
              af[rt], bf[ct], acc[rt][ct], 0, 0, 0);
    }
  }

  // Epilogue: C/D layout col=lane&15, row=quad*4+reg [m89-verified].
  // Reduce max over this block's 128 cols per row, split j<i / j>i.
  const int rowBase = rowTile + wr * 64;
  const int colBase = colTile + wc * 64;
  #pragma unroll
  for (int rt = 0; rt < 4; ++rt) {
    #pragma unroll
    for (int reg = 0; reg < 4; ++reg) {
      int i = rowBase + rt * 16 + quad * 4 + reg;
      float lt = -3.0e38f, gt = -3.0e38f;
      #pragma unroll
      for (int ct = 0; ct < 4; ++ct) {
        int j = colBase + ct * 16 + m;
        float v = acc[rt][ct][reg];
        if (j < i) lt = fmaxf(lt, v);
        else if (j > i) gt = fmaxf(gt, v);
      }
      // butterfly across the 16 lanes of this quad (same rows, diff cols)
      #pragma unroll
      for (int mk = 1; mk < 16; mk <<= 1) {
        lt = fmaxf(lt, __shfl_xor(lt, mk));
        gt = fmaxf(gt, __shfl_xor(gt, mk));
      }
      if (m == 0) {
        atomicMax(&maxLT[(size_t)z * BB + i], fmap(lt));
        atomicMax(&maxGT[(size_t)z * BB + i], fmap(gt));
      }
    }
  }
}

// ---------------------------------------------------------------------------
// Phase 3: per-row verdicts -> per-matrix correct counts.
// argmax==i  <=>  diag > maxLT  &&  diag >= maxGT   (first-index tie rule)
// ---------------------------------------------------------------------------
__global__ __launch_bounds__(256) void phase3(
    const float* __restrict__ diag, const unsigned* __restrict__ maxLT,
    const unsigned* __restrict__ maxGT, float* __restrict__ counts) {
  int r = blockIdx.x * 256 + threadIdx.x;
  int lane = threadIdx.x & 63;
  float c[3];
  #pragma unroll
  for (int z = 0; z < 3; ++z) {
    unsigned md = fmap(diag[z * BB + r]);
    c[z] = (md > maxLT[z * BB + r] && md >= maxGT[z * BB + r]) ? 1.f : 0.f;
  }
  #pragma unroll
  for (int mk = 1; mk < 64; mk <<= 1) {
    #pragma unroll
    for (int z = 0; z < 3; ++z) c[z] += __shfl_xor(c[z], mk);
  }
  if (lane == 0) {
    #pragma unroll
    for (int z = 0; z < 3; ++z) atomicAdd(&counts[z], c[z]);
  }
}

__global__ void finalize(const float* __restrict__ lossSums,
                         const float* __restrict__ counts,
                         float* __restrict__ out) {
  if (threadIdx.x == 0) {
    float vl = 1.f - lossSums[0] * (1.f / BB);
    float tl = 1.f - lossSums[1] * (1.f / BB);
    out[0] = vl;
    out[1] = tl;
    out[2] = vl + tl;
    float a0 = counts[0] * (100.f / BB);
    float a1 = counts[1] * (100.f / BB);
    float a2 = counts[2] * (100.f / BB);
    out[3] = a0;  // gt_v - gt_t
    out[4] = a1;  // v    - gt_t
    out[5] = a0;  // gt_v - t   (t side is gt_t in the original code)
    out[6] = a1;  // v    - t
    out[7] = a2;  // narr - gt_t
    out[8] = a2;  // narr - t
  }
}

extern "C" void kernel_launch(void* const* d_in, const int* in_sizes, int n_in,
                              void* d_out, int out_size, void* d_ws, size_t ws_size,
                              hipStream_t stream) {
  const float* vp  = (const float*)d_in[0];
  const float* tp  = (const float*)d_in[1];
  const float* vfp = (const float*)d_in[2];
  const float* ce  = (const float*)d_in[3];
  const float* nr  = (const float*)d_in[4];

  char* ws = (char*)d_ws;
  float*    lossSums = (float*)ws;                  // 2 floats
  float*    counts   = lossSums + 2;                // 3 floats
  unsigned* maxLT    = (unsigned*)(ws + 64);        // 3*BB uints
  unsigned* maxGT    = maxLT + 3 * BB;              // 3*BB uints
  float*    diag     = (float*)(maxGT + 3 * BB);    // 3*BB floats
  u16*      gvbuf    = (u16*)(diag + 3 * BB);       // BB*DIM bf16 each
  u16*      vbuf     = gvbuf + (size_t)BB * DIM;
  u16*      nvbuf    = vbuf  + (size_t)BB * DIM;
  u16*      gtbuf    = nvbuf + (size_t)BB * DIM;

  // zero accumulators (lossSums, counts, maxLT, maxGT)
  hipMemsetAsync(ws, 0, 64 + (size_t)3 * BB * 4 * 2, stream);

  phase1<<<BB / 4, 256, 0, stream>>>(vp, tp, vfp, ce, nr, lossSums, diag,
                                     vbuf, gvbuf, nvbuf, gtbuf);

  dim3 grid(BB / 128, BB / 128, 3);
  sim_argmax<<<grid, 256, 0, stream>>>(gvbuf, vbuf, nvbuf, gtbuf, maxLT, maxGT);

  phase3<<<BB / 256, 256, 0, stream>>>(diag, maxLT, maxGT, counts);
  finalize<<<1, 64, 0, stream>>>(lossSums, counts, (float*)d_out);
}

// Round 2
// 324.961 us; speedup vs baseline: 2.1718x; 2.1718x over previous
//
#include <hip/hip_runtime.h>
#include <hip/hip_bf16.h>
#include <stdint.h>

#define BB 8192
#define DIM 256

typedef unsigned short u16;
typedef __attribute__((ext_vector_type(8))) short bf16x8;   // 8 bf16 = 4 VGPRs
typedef __attribute__((ext_vector_type(4))) float f32x4;

// monotone float -> uint mapping (order-preserving), so atomicMax(uint) == float max
__device__ __forceinline__ unsigned fmap(float f) {
  unsigned u = __float_as_uint(f);
  return (u & 0x80000000u) ? ~u : (u | 0x80000000u);
}

__device__ __forceinline__ u16 f2bf(float f) {
  __hip_bfloat16 h = __float2bfloat16(f);   // RTNE
  union { __hip_bfloat16 h; u16 u; } cvt;
  cvt.h = h;
  return cvt.u;
}

// async global->LDS, 16B per lane. LDS dest must be wave-uniform base + lane*16.
__device__ __forceinline__ void load_lds16(const u16* g, u16* l) {
  __builtin_amdgcn_global_load_lds(
      (const __attribute__((address_space(1))) unsigned int*)g,
      (__attribute__((address_space(3))) unsigned int*)l, 16, 0, 0);
}

// ---------------------------------------------------------------------------
// Phase 1: one wave per row. Row-wise dots/norms, per-row cos (NO same-address
// atomics), fp32 diagonal sims, 4 normalized bf16 matrices to ws.
// ---------------------------------------------------------------------------
__global__ __launch_bounds__(256) void phase1(
    const float* __restrict__ vp,  const float* __restrict__ tp,
    const float* __restrict__ vfp, const float* __restrict__ ce,
    const float* __restrict__ nr,
    float* __restrict__ rowcos, float* __restrict__ diag,
    u16* __restrict__ vbuf, u16* __restrict__ gvbuf,
    u16* __restrict__ nvbuf, u16* __restrict__ gtbuf) {
  const int wave = threadIdx.x >> 6;
  const int lane = threadIdx.x & 63;
  const int row  = blockIdx.x * 4 + wave;
  const int base = row * DIM + lane * 4;

  float4 a = *(const float4*)&vp[base];
  float4 t = *(const float4*)&tp[base];
  float4 g = *(const float4*)&vfp[base];
  float4 c = *(const float4*)&ce[base];
  float4 n = *(const float4*)&nr[base];

  float s[10];
  s[0] = a.x*a.x + a.y*a.y + a.z*a.z + a.w*a.w;  // |vp|^2
  s[1] = g.x*g.x + g.y*g.y + g.z*g.z + g.w*g.w;  // |vfp|^2
  s[2] = a.x*g.x + a.y*g.y + a.z*g.z + a.w*g.w;  // vp.vfp
  s[3] = t.x*t.x + t.y*t.y + t.z*t.z + t.w*t.w;  // |tp|^2
  s[4] = c.x*c.x + c.y*c.y + c.z*c.z + c.w*c.w;  // |ce|^2
  s[5] = t.x*c.x + t.y*c.y + t.z*c.z + t.w*c.w;  // tp.ce
  s[6] = n.x*n.x + n.y*n.y + n.z*n.z + n.w*n.w;  // |narr|^2
  s[7] = g.x*c.x + g.y*c.y + g.z*c.z + g.w*c.w;  // vfp.ce
  s[8] = a.x*c.x + a.y*c.y + a.z*c.z + a.w*c.w;  // vp.ce
  s[9] = n.x*c.x + n.y*c.y + n.z*c.z + n.w*c.w;  // narr.ce

  #pragma unroll
  for (int mk = 1; mk < 64; mk <<= 1) {
    #pragma unroll
    for (int q = 0; q < 10; ++q) s[q] += __shfl_xor(s[q], mk);
  }

  const float eps = 1e-8f;
  float na = fmaxf(sqrtf(s[0]), eps);
  float ng = fmaxf(sqrtf(s[1]), eps);
  float nt = fmaxf(sqrtf(s[3]), eps);
  float nc = fmaxf(sqrtf(s[4]), eps);
  float nn = fmaxf(sqrtf(s[6]), eps);

  float ia = 1.f / na, ig = 1.f / ng, ic = 1.f / nc, in_ = 1.f / nn;

  ushort4* v4  = (ushort4*)vbuf;
  ushort4* gv4 = (ushort4*)gvbuf;
  ushort4* nv4 = (ushort4*)nvbuf;
  ushort4* gt4 = (ushort4*)gtbuf;
  int idx = row * 64 + lane;
  v4[idx]  = make_ushort4(f2bf(a.x*ia),  f2bf(a.y*ia),  f2bf(a.z*ia),  f2bf(a.w*ia));
  gv4[idx] = make_ushort4(f2bf(g.x*ig),  f2bf(g.y*ig),  f2bf(g.z*ig),  f2bf(g.w*ig));
  nv4[idx] = make_ushort4(f2bf(n.x*in_), f2bf(n.y*in_), f2bf(n.z*in_), f2bf(n.w*in_));
  gt4[idx] = make_ushort4(f2bf(c.x*ic),  f2bf(c.y*ic),  f2bf(c.z*ic),  f2bf(c.w*ic));

  if (lane == 0) {
    rowcos[row]      = s[2] / (na * ng);     // vis cos
    rowcos[BB + row] = s[5] / (nt * nc);     // text cos
    diag[0 * BB + row] = s[7] / (ng * nc);   // gt_v . gt_t
    diag[1 * BB + row] = s[8] / (na * nc);   // v    . gt_t
    diag[2 * BB + row] = s[9] / (nn * nc);   // narr . gt_t
  }
}

// ---------------------------------------------------------------------------
// Phase 2: fused bf16-MFMA B^T GEMM + per-row LT/GT running max.
// m97 structure: 128x128 tile, BK=64, global_load_lds width 16 (unpadded LDS,
// stride 64 -- the DMA requires contiguous lane order), 4 waves (2x2 of
// 64x64), 16x16x32 MFMA. grid.z selects the A matrix (gt_v / v / narr_v).
// Epilogue: LDS-combine across column-waves, then dense atomicMax.
// ---------------------------------------------------------------------------
__global__ __launch_bounds__(256) void sim_argmax(
    const u16* __restrict__ Abase, const u16* __restrict__ B,
    unsigned* __restrict__ maxLT, unsigned* __restrict__ maxGT) {
  __shared__ u16 As[128 * 64];
  __shared__ u16 Bs[128 * 64];
  __shared__ float ltb[128][2];
  __shared__ float gtb[128][2];

  const int tid  = threadIdx.x;
  const int lane = tid & 63;
  const int wave = tid >> 6;
  const int wr   = wave >> 1, wc = wave & 1;
  const int m    = lane & 15, quad = lane >> 4;
  const int z    = blockIdx.z;

  const u16* A = Abase + (size_t)z * BB * DIM;
  const int rowTile = blockIdx.y * 128;
  const int colTile = blockIdx.x * 128;

  f32x4 acc[4][4];
  #pragma unroll
  for (int i = 0; i < 4; ++i)
    #pragma unroll
    for (int j = 0; j < 4; ++j) acc[i][j] = (f32x4){0.f, 0.f, 0.f, 0.f};

  for (int s = 0; s < 4; ++s) {
    const int k0 = s * 64;
    if (s) __syncthreads();   // prev-stage ds_reads done before overwrite
    // stage 128 rows x 64 cols of A and B: 1024 16B chunks each, DMA'd.
    // chunk = (wave*4 + t)*64 + lane -> LDS offset chunk*16B (lane-contig).
    #pragma unroll
    for (int t = 0; t < 4; ++t) {
      int chunk = (wave * 4 + t) * 64 + lane;
      int row = chunk >> 3, c8 = chunk & 7;
      load_lds16(&A[(size_t)(rowTile + row) * DIM + k0 + c8 * 8], &As[chunk * 8]);
      load_lds16(&B[(size_t)(colTile + row) * DIM + k0 + c8 * 8], &Bs[chunk * 8]);
    }
    __syncthreads();          // vmcnt(0) drain + barrier

    #pragma unroll
    for (int kk = 0; kk < 2; ++kk) {
      bf16x8 af[4], bf[4];
      #pragma unroll
      for (int rt = 0; rt < 4; ++rt)
        af[rt] = *(const bf16x8*)&As[(wr * 64 + rt * 16 + m) * 64 + kk * 32 + quad * 8];
      #pragma unroll
      for (int ct = 0; ct < 4; ++ct)
        bf[ct] = *(const bf16x8*)&Bs[(wc * 64 + ct * 16 + m) * 64 + kk * 32 + quad * 8];
      #pragma unroll
      for (int rt = 0; rt < 4; ++rt)
        #pragma unroll
        for (int ct = 0; ct < 4; ++ct)
          acc[rt][ct] = __builtin_amdgcn_mfma_f32_16x16x32_bf16(
              af[rt], bf[ct], acc[rt][ct], 0, 0, 0);
    }
  }

  // Epilogue: C/D layout col=lane&15, row=quad*4+reg [m89-verified].
  const int rowBase = rowTile + wr * 64;
  const int colBase = colTile + wc * 64;
  #pragma unroll
  for (int rt = 0; rt < 4; ++rt) {
    #pragma unroll
    for (int reg = 0; reg < 4; ++reg) {
      int i = rowBase + rt * 16 + quad * 4 + reg;
      float lt = -3.0e38f, gt = -3.0e38f;
      #pragma unroll
      for (int ct = 0; ct < 4; ++ct) {
        int j = colBase + ct * 16 + m;
        float v = acc[rt][ct][reg];
        if (j < i) lt = fmaxf(lt, v);
        else if (j > i) gt = fmaxf(gt, v);
      }
      #pragma unroll
      for (int mk = 1; mk < 16; mk <<= 1) {
        lt = fmaxf(lt, __shfl_xor(lt, mk));
        gt = fmaxf(gt, __shfl_xor(gt, mk));
      }
      if (m == 0) {
        int ri = wr * 64 + rt * 16 + quad * 4 + reg;
        ltb[ri][wc] = lt;
        gtb[ri][wc] = gt;
      }
    }
  }
  __syncthreads();
  if (tid < 128) {
    float lt = fmaxf(ltb[tid][0], ltb[tid][1]);
    float gt = fmaxf(gtb[tid][0], gtb[tid][1]);
    size_t off = (size_t)z * BB + rowTile + tid;
    atomicMax(&maxLT[off], fmap(lt));   // dense: all 64 lanes active
    atomicMax(&maxGT[off], fmap(gt));
  }
}

// ---------------------------------------------------------------------------
// Phase 3: per-row verdicts + loss sums -> 5 scalars (block-reduced, then one
// atomic per scalar per block; 32 blocks total).
// argmax==i  <=>  diag > maxLT  &&  diag >= maxGT   (first-index tie rule)
// ---------------------------------------------------------------------------
__global__ __launch_bounds__(256) void phase3(
    const float* __restrict__ diag, const unsigned* __restrict__ maxLT,
    const unsigned* __restrict__ maxGT, const float* __restrict__ rowcos,
    float* __restrict__ sums) {   // sums[0..1]=loss cos sums, sums[2..4]=counts
  __shared__ float red[4][5];
  int r = blockIdx.x * 256 + threadIdx.x;
  int lane = threadIdx.x & 63, wave = threadIdx.x >> 6;
  float v[5];
  v[0] = rowcos[r];
  v[1] = rowcos[BB + r];
  #pragma unroll
  for (int z = 0; z < 3; ++z) {
    unsigned md = fmap(diag[z * BB + r]);
    v[2 + z] = (md > maxLT[z * BB + r] && md >= maxGT[z * BB + r]) ? 1.f : 0.f;
  }
  #pragma unroll
  for (int mk = 1; mk < 64; mk <<= 1) {
    #pragma unroll
    for (int q = 0; q < 5; ++q) v[q] += __shfl_xor(v[q], mk);
  }
  if (lane == 0) {
    #pragma unroll
    for (int q = 0; q < 5; ++q) red[wave][q] = v[q];
  }
  __syncthreads();
  if (threadIdx.x < 5) {
    float acc = red[0][threadIdx.x] + red[1][threadIdx.x] +
                red[2][threadIdx.x] + red[3][threadIdx.x];
    atomicAdd(&sums[threadIdx.x], acc);
  }
}

__global__ void finalize(const float* __restrict__ sums, float* __restrict__ out) {
  if (threadIdx.x == 0) {
    float vl = 1.f - sums[0] * (1.f / BB);
    float tl = 1.f - sums[1] * (1.f / BB);
    out[0] = vl;
    out[1] = tl;
    out[2] = vl + tl;
    float a0 = sums[2] * (100.f / BB);
    float a1 = sums[3] * (100.f / BB);
    float a2 = sums[4] * (100.f / BB);
    out[3] = a0;  // gt_v - gt_t
    out[4] = a1;  // v    - gt_t
    out[5] = a0;  // gt_v - t   (t side is gt_t in the original code)
    out[6] = a1;  // v    - t
    out[7] = a2;  // narr - gt_t
    out[8] = a2;  // narr - t
  }
}

extern "C" void kernel_launch(void* const* d_in, const int* in_sizes, int n_in,
                              void* d_out, int out_size, void* d_ws, size_t ws_size,
                              hipStream_t stream) {
  const float* vp  = (const float*)d_in[0];
  const float* tp  = (const float*)d_in[1];
  const float* vfp = (const float*)d_in[2];
  const float* ce  = (const float*)d_in[3];
  const float* nr  = (const float*)d_in[4];

  char* ws = (char*)d_ws;
  float*    sums  = (float*)ws;                     // 5 floats (2 loss + 3 counts)
  unsigned* maxLT = (unsigned*)(ws + 64);           // 3*BB uints
  unsigned* maxGT = maxLT + 3 * BB;                 // 3*BB uints
  float*    diag  = (float*)(maxGT + 3 * BB);       // 3*BB floats
  float*    rowcos= diag + 3 * BB;                  // 2*BB floats
  u16*      gvbuf = (u16*)(rowcos + 2 * BB);        // BB*DIM bf16 each; z-order:
  u16*      vbuf  = gvbuf + (size_t)BB * DIM;       //   z=0 gt_v, z=1 v, z=2 narr
  u16*      nvbuf = vbuf  + (size_t)BB * DIM;
  u16*      gtbuf = nvbuf + (size_t)BB * DIM;

  // zero accumulators (sums, maxLT, maxGT)
  hipMemsetAsync(ws, 0, 64 + (size_t)3 * BB * 4 * 2, stream);

  phase1<<<BB / 4, 256, 0, stream>>>(vp, tp, vfp, ce, nr, rowcos, diag,
                                     vbuf, gvbuf, nvbuf, gtbuf);

  dim3 grid(BB / 128, BB / 128, 3);
  sim_argmax<<<grid, 256, 0, stream>>>(gvbuf, gtbuf, maxLT, maxGT);

  phase3<<<BB / 256, 256, 0, stream>>>(diag, maxLT, maxGT, rowcos, sums);
  finalize<<<1, 64, 0, stream>>>(sums, (float*)d_out);
}

// Round 3
// 290.522 us; speedup vs baseline: 2.4293x; 1.1185x over previous
//
#include <hip/hip_runtime.h>
#include <hip/hip_bf16.h>
#include <stdint.h>

#define BB 8192
#define DIM 256

typedef unsigned short u16;
typedef __attribute__((ext_vector_type(8))) short bf16x8;   // 8 bf16 = 4 VGPRs
typedef __attribute__((ext_vector_type(4))) float f32x4;

// monotone float -> uint mapping (order-preserving), so atomicMax(uint) == float max
__device__ __forceinline__ unsigned fmap(float f) {
  unsigned u = __float_as_uint(f);
  return (u & 0x80000000u) ? ~u : (u | 0x80000000u);
}

__device__ __forceinline__ u16 f2bf(float f) {
  __hip_bfloat16 h = __float2bfloat16(f);   // RTNE
  union { __hip_bfloat16 h; u16 u; } cvt;
  cvt.h = h;
  return cvt.u;
}

// async global->LDS, 16B per lane. LDS dest must be wave-uniform base + lane*16.
__device__ __forceinline__ void load_lds16(const u16* g, u16* l) {
  __builtin_amdgcn_global_load_lds(
      (const __attribute__((address_space(1))) unsigned int*)g,
      (__attribute__((address_space(3))) unsigned int*)l, 16, 0, 0);
}

// ---------------------------------------------------------------------------
// Phase 1: one wave per row. Row-wise dots/norms, per-row cos (NO same-address
// atomics), fp32 diagonal sims, 4 normalized bf16 matrices to ws.
// ---------------------------------------------------------------------------
__global__ __launch_bounds__(256) void phase1(
    const float* __restrict__ vp,  const float* __restrict__ tp,
    const float* __restrict__ vfp, const float* __restrict__ ce,
    const float* __restrict__ nr,
    float* __restrict__ rowcos, float* __restrict__ diag,
    u16* __restrict__ vbuf, u16* __restrict__ gvbuf,
    u16* __restrict__ nvbuf, u16* __restrict__ gtbuf) {
  const int wave = threadIdx.x >> 6;
  const int lane = threadIdx.x & 63;
  const int row  = blockIdx.x * 4 + wave;
  const int base = row * DIM + lane * 4;

  float4 a = *(const float4*)&vp[base];
  float4 t = *(const float4*)&tp[base];
  float4 g = *(const float4*)&vfp[base];
  float4 c = *(const float4*)&ce[base];
  float4 n = *(const float4*)&nr[base];

  float s[10];
  s[0] = a.x*a.x + a.y*a.y + a.z*a.z + a.w*a.w;  // |vp|^2
  s[1] = g.x*g.x + g.y*g.y + g.z*g.z + g.w*g.w;  // |vfp|^2
  s[2] = a.x*g.x + a.y*g.y + a.z*g.z + a.w*g.w;  // vp.vfp
  s[3] = t.x*t.x + t.y*t.y + t.z*t.z + t.w*t.w;  // |tp|^2
  s[4] = c.x*c.x + c.y*c.y + c.z*c.z + c.w*c.w;  // |ce|^2
  s[5] = t.x*c.x + t.y*c.y + t.z*c.z + t.w*c.w;  // tp.ce
  s[6] = n.x*n.x + n.y*n.y + n.z*n.z + n.w*n.w;  // |narr|^2
  s[7] = g.x*c.x + g.y*c.y + g.z*c.z + g.w*c.w;  // vfp.ce
  s[8] = a.x*c.x + a.y*c.y + a.z*c.z + a.w*c.w;  // vp.ce
  s[9] = n.x*c.x + n.y*c.y + n.z*c.z + n.w*c.w;  // narr.ce

  #pragma unroll
  for (int mk = 1; mk < 64; mk <<= 1) {
    #pragma unroll
    for (int q = 0; q < 10; ++q) s[q] += __shfl_xor(s[q], mk);
  }

  const float eps = 1e-8f;
  float na = fmaxf(sqrtf(s[0]), eps);
  float ng = fmaxf(sqrtf(s[1]), eps);
  float nt = fmaxf(sqrtf(s[3]), eps);
  float nc = fmaxf(sqrtf(s[4]), eps);
  float nn = fmaxf(sqrtf(s[6]), eps);

  float ia = 1.f / na, ig = 1.f / ng, ic = 1.f / nc, in_ = 1.f / nn;

  ushort4* v4  = (ushort4*)vbuf;
  ushort4* gv4 = (ushort4*)gvbuf;
  ushort4* nv4 = (ushort4*)nvbuf;
  ushort4* gt4 = (ushort4*)gtbuf;
  int idx = row * 64 + lane;
  v4[idx]  = make_ushort4(f2bf(a.x*ia),  f2bf(a.y*ia),  f2bf(a.z*ia),  f2bf(a.w*ia));
  gv4[idx] = make_ushort4(f2bf(g.x*ig),  f2bf(g.y*ig),  f2bf(g.z*ig),  f2bf(g.w*ig));
  nv4[idx] = make_ushort4(f2bf(n.x*in_), f2bf(n.y*in_), f2bf(n.z*in_), f2bf(n.w*in_));
  gt4[idx] = make_ushort4(f2bf(c.x*ic),  f2bf(c.y*ic),  f2bf(c.z*ic),  f2bf(c.w*ic));

  if (lane == 0) {
    rowcos[row]      = s[2] / (na * ng);     // vis cos
    rowcos[BB + row] = s[5] / (nt * nc);     // text cos
    diag[0 * BB + row] = s[7] / (ng * nc);   // gt_v . gt_t
    diag[1 * BB + row] = s[8] / (na * nc);   // v    . gt_t
    diag[2 * BB + row] = s[9] / (nn * nc);   // narr . gt_t
  }
}

// ---------------------------------------------------------------------------
// Phase 2: fused bf16-MFMA B^T GEMM + per-row LT/GT running max.
// 128x128 tile, BK=64, global_load_lds width 16, 4 waves (2x2 of 64x64),
// 16x16x32 MFMA. LDS chunk layout is XOR-swizzled: logical (row, c8) lives at
// physical chunk row*8 + (c8 ^ (row&7)). The DMA writes physical chunks in
// lane order (required); fragment ds_read_b128 then lands on bank-group
// 4*((kk*4+quad) ^ (m&7)) -> 2 lanes/group = conflict-free (m136: 2-way free).
// grid.z selects the A matrix (gt_v / v / narr_v).
// ---------------------------------------------------------------------------
__global__ __launch_bounds__(256) void sim_argmax(
    const u16* __restrict__ Abase, const u16* __restrict__ B,
    unsigned* __restrict__ maxLT, unsigned* __restrict__ maxGT) {
  __shared__ u16 As[128 * 64];
  __shared__ u16 Bs[128 * 64];
  __shared__ float ltb[128][2];
  __shared__ float gtb[128][2];

  const int tid  = threadIdx.x;
  const int lane = tid & 63;
  const int wave = tid >> 6;
  const int wr   = wave >> 1, wc = wave & 1;
  const int m    = lane & 15, quad = lane >> 4;
  const int z    = blockIdx.z;

  const u16* A = Abase + (size_t)z * BB * DIM;
  const int rowTile = blockIdx.y * 128;
  const int colTile = blockIdx.x * 128;

  f32x4 acc[4][4];
  #pragma unroll
  for (int i = 0; i < 4; ++i)
    #pragma unroll
    for (int j = 0; j < 4; ++j) acc[i][j] = (f32x4){0.f, 0.f, 0.f, 0.f};

  for (int s = 0; s < 4; ++s) {
    const int k0 = s * 64;
    if (s) __syncthreads();   // prev-stage ds_reads done before overwrite
    // stage 128 rows x 64 cols of A and B, XOR-swizzled chunk placement
    #pragma unroll
    for (int t = 0; t < 4; ++t) {
      int c   = (wave * 4 + t) * 64 + lane;       // physical chunk
      int row = c >> 3;
      int c8  = (c & 7) ^ (row & 7);              // logical 16B chunk in row
      load_lds16(&A[(size_t)(rowTile + row) * DIM + k0 + c8 * 8], &As[c * 8]);
      load_lds16(&B[(size_t)(colTile + row) * DIM + k0 + c8 * 8], &Bs[c * 8]);
    }
    __syncthreads();          // vmcnt(0) drain + barrier

    const int axor = m & 7;
    #pragma unroll
    for (int kk = 0; kk < 2; ++kk) {
      const int kc8 = (kk * 4 + quad);
      bf16x8 af[4], bf[4];
      #pragma unroll
      for (int rt = 0; rt < 4; ++rt) {
        int ar = wr * 64 + rt * 16 + m;           // ar&7 == m&7
        af[rt] = *(const bf16x8*)&As[ar * 64 + ((kc8 ^ axor) * 8)];
      }
      #pragma unroll
      for (int ct = 0; ct < 4; ++ct) {
        int br = wc * 64 + ct * 16 + m;
        bf[ct] = *(const bf16x8*)&Bs[br * 64 + ((kc8 ^ axor) * 8)];
      }
      #pragma unroll
      for (int rt = 0; rt < 4; ++rt)
        #pragma unroll
        for (int ct = 0; ct < 4; ++ct)
          acc[rt][ct] = __builtin_amdgcn_mfma_f32_16x16x32_bf16(
              af[rt], bf[ct], acc[rt][ct], 0, 0, 0);
    }
  }

  // Epilogue: C/D layout col=lane&15, row=quad*4+reg [m89-verified].
  const int rowBase = rowTile + wr * 64;
  const int colBase = colTile + wc * 64;
  #pragma unroll
  for (int rt = 0; rt < 4; ++rt) {
    #pragma unroll
    for (int reg = 0; reg < 4; ++reg) {
      int i = rowBase + rt * 16 + quad * 4 + reg;
      float lt = -3.0e38f, gt = -3.0e38f;
      #pragma unroll
      for (int ct = 0; ct < 4; ++ct) {
        int j = colBase + ct * 16 + m;
        float v = acc[rt][ct][reg];
        if (j < i) lt = fmaxf(lt, v);
        else if (j > i) gt = fmaxf(gt, v);
      }
      #pragma unroll
      for (int mk = 1; mk < 16; mk <<= 1) {
        lt = fmaxf(lt, __shfl_xor(lt, mk));
        gt = fmaxf(gt, __shfl_xor(gt, mk));
      }
      if (m == 0) {
        int ri = wr * 64 + rt * 16 + quad * 4 + reg;
        ltb[ri][wc] = lt;
        gtb[ri][wc] = gt;
      }
    }
  }
  __syncthreads();
  if (tid < 128) {
    float lt = fmaxf(ltb[tid][0], ltb[tid][1]);
    float gt = fmaxf(gtb[tid][0], gtb[tid][1]);
    size_t off = (size_t)z * BB + rowTile + tid;
    atomicMax(&maxLT[off], fmap(lt));   // dense: all 64 lanes active
    atomicMax(&maxGT[off], fmap(gt));
  }
}

// ---------------------------------------------------------------------------
// Phase 3: per-row verdicts + loss sums -> 5 scalars (block-reduced, then one
// atomic per scalar per block; 32 blocks total).
// argmax==i  <=>  diag > maxLT  &&  diag >= maxGT   (first-index tie rule)
// ---------------------------------------------------------------------------
__global__ __launch_bounds__(256) void phase3(
    const float* __restrict__ diag, const unsigned* __restrict__ maxLT,
    const unsigned* __restrict__ maxGT, const float* __restrict__ rowcos,
    float* __restrict__ sums) {   // sums[0..1]=loss cos sums, sums[2..4]=counts
  __shared__ float red[4][5];
  int r = blockIdx.x * 256 + threadIdx.x;
  int lane = threadIdx.x & 63, wave = threadIdx.x >> 6;
  float v[5];
  v[0] = rowcos[r];
  v[1] = rowcos[BB + r];
  #pragma unroll
  for (int z = 0; z < 3; ++z) {
    unsigned md = fmap(diag[z * BB + r]);
    v[2 + z] = (md > maxLT[z * BB + r] && md >= maxGT[z * BB + r]) ? 1.f : 0.f;
  }
  #pragma unroll
  for (int mk = 1; mk < 64; mk <<= 1) {
    #pragma unroll
    for (int q = 0; q < 5; ++q) v[q] += __shfl_xor(v[q], mk);
  }
  if (lane == 0) {
    #pragma unroll
    for (int q = 0; q < 5; ++q) red[wave][q] = v[q];
  }
  __syncthreads();
  if (threadIdx.x < 5) {
    float acc = red[0][threadIdx.x] + red[1][threadIdx.x] +
                red[2][threadIdx.x] + red[3][threadIdx.x];
    atomicAdd(&sums[threadIdx.x], acc);
  }
}

__global__ void finalize(const float* __restrict__ sums, float* __restrict__ out) {
  if (threadIdx.x == 0) {
    float vl = 1.f - sums[0] * (1.f / BB);
    float tl = 1.f - sums[1] * (1.f / BB);
    out[0] = vl;
    out[1] = tl;
    out[2] = vl + tl;
    float a0 = sums[2] * (100.f / BB);
    float a1 = sums[3] * (100.f / BB);
    float a2 = sums[4] * (100.f / BB);
    out[3] = a0;  // gt_v - gt_t
    out[4] = a1;  // v    - gt_t
    out[5] = a0;  // gt_v - t   (t side is gt_t in the original code)
    out[6] = a1;  // v    - t
    out[7] = a2;  // narr - gt_t
    out[8] = a2;  // narr - t
  }
}

extern "C" void kernel_launch(void* const* d_in, const int* in_sizes, int n_in,
                              void* d_out, int out_size, void* d_ws, size_t ws_size,
                              hipStream_t stream) {
  const float* vp  = (const float*)d_in[0];
  const float* tp  = (const float*)d_in[1];
  const float* vfp = (const float*)d_in[2];
  const float* ce  = (const float*)d_in[3];
  const float* nr  = (const float*)d_in[4];

  char* ws = (char*)d_ws;
  float*    sums  = (float*)ws;                     // 5 floats (2 loss + 3 counts)
  unsigned* maxLT = (unsigned*)(ws + 64);           // 3*BB uints
  unsigned* maxGT = maxLT + 3 * BB;                 // 3*BB uints
  float*    diag  = (float*)(maxGT + 3 * BB);       // 3*BB floats
  float*    rowcos= diag + 3 * BB;                  // 2*BB floats
  u16*      gvbuf = (u16*)(rowcos + 2 * BB);        // BB*DIM bf16 each; z-order:
  u16*      vbuf  = gvbuf + (size_t)BB * DIM;       //   z=0 gt_v, z=1 v, z=2 narr
  u16*      nvbuf = vbuf  + (size_t)BB * DIM;
  u16*      gtbuf = nvbuf + (size_t)BB * DIM;

  // zero accumulators (sums, maxLT, maxGT)
  hipMemsetAsync(ws, 0, 64 + (size_t)3 * BB * 4 * 2, stream);

  phase1<<<BB / 4, 256, 0, stream>>>(vp, tp, vfp, ce, nr, rowcos, diag,
                                     vbuf, gvbuf, nvbuf, gtbuf);

  dim3 grid(BB / 128, BB / 128, 3);
  sim_argmax<<<grid, 256, 0, stream>>>(gvbuf, gtbuf, maxLT, maxGT);

  phase3<<<BB / 256, 256, 0, stream>>>(diag, maxLT, maxGT, rowcos, sums);
  finalize<<<1, 64, 0, stream>>>(sums, (float*)d_out);
}